// Round 3
// baseline (1124.046 us; speedup 1.0000x reference)
//
#include <hip/hip_runtime.h>
#include <math.h>

#define ALIGN16 __attribute__((aligned(16)))

__device__ __forceinline__ float rcpf_(float x){ return __builtin_amdgcn_rcpf(x); }
__device__ __forceinline__ float tanh_e(float x){
  float t = __expf(2.0f*x);
  return (t - 1.0f) * rcpf_(t + 1.0f);
}
__device__ __forceinline__ float sigm(float x){
  return rcpf_(1.0f + __expf(-x));
}

// One block of 1024 threads (16 waves) per batch element; 256 blocks, 1/CU.
// VGPR <= 128 (4 waves/SIMD, 50% occupancy). LSTM state (h,c) is register-
// resident per lane (j = lane), redundantly maintained by every wave ->
// 3 barriers/step, no serial section. Roles per phase:
//   A/update: u = tid>>4 (64), g16 = tid&15 (j-slice of 4, shfl state)
//   enc-C:    f = tid>>2 (256), q4 = tid&3 (u-slice of 16)
//   z:        k = tid>>2 (256), q4 (reduction quarter)
// Decoder fc-layer folded: XM = xenc @ (fcW_ctx @ dK) precomputed once ->
// per-step context phase eliminated.
__global__ __launch_bounds__(1024, 4)
void darnn_fused(const float* __restrict__ gin,   // [256][64][256]
                 const float* __restrict__ eKg,   // [256][256]
                 const float* __restrict__ eRg,   // [64][256]
                 const float* __restrict__ ebg,   // [256]
                 const float* __restrict__ dKg,   // [64][256]
                 const float* __restrict__ dRg,   // [64][256]
                 const float* __restrict__ dbg,   // [256]
                 const float* __restrict__ aeW,   // [192][64]
                 const float* __restrict__ aeb,   // [64]
                 const float* __restrict__ aev,   // [64]
                 const float* __restrict__ adW,   // [192][64]
                 const float* __restrict__ adb,   // [64]
                 const float* __restrict__ adv,   // [64]
                 const float* __restrict__ fcW,   // [65][64]
                 const float* __restrict__ fcb,   // [64]
                 const float* __restrict__ fcfW,  // [128][256]
                 const float* __restrict__ fcfb,  // [256]
                 float* __restrict__ out)         // [256][256]
{
  __shared__ ALIGN16 float s_buf[17408];   // We_x -> eR[64][257] -> M1T[256][68] -> dR[64][257]
  __shared__ ALIGN16 float s_wx2[17408];   // Wd_x -> fcW(4160) -> XMT[256][68]
  __shared__ ALIGN16 float s_xenc[64*68];  // x_encoded, stride 68
  __shared__ ALIGN16 float s_ag[256];      // activated gates
  __shared__ ALIGN16 float s_xtld[256];    // unnormalized x_tilde
  __shared__ ALIGN16 float s_hs[64];       // E_u = exp(2*preact_u)
  __shared__ ALIGN16 float s_pe[64];       // decoder unnorm softmax
  __shared__ ALIGN16 float s_redB[16];     // per-wave softmax partials
  __shared__ ALIGN16 float s_ctx[64];
  __shared__ ALIGN16 float s_yprev[64];
  __shared__ ALIGN16 float s_fcb[64];
  __shared__ ALIGN16 float s_h[64];        // h (enc) / d (dec) for z-phase
  __shared__ ALIGN16 float s_aev[64];

  const int tid  = threadIdx.x;
  const int lane = tid & 63;
  const int wv   = tid >> 6;   // 0..15
  const int u    = tid >> 4;   // 0..63
  const int g16  = tid & 15;
  const int f    = tid >> 2;   // 0..255 (also k, also o)
  const int q4   = tid & 3;
  const int b    = blockIdx.x;
  const float* inb = gin + (size_t)b * (64*256);

  // ================= encoder prologue =================
  for (int i = tid; i < 4096; i += 1024) s_buf[i] = aeW[8192 + i];   // We_x
  if (tid < 64) { s_aev[tid] = aev[tid]; s_h[tid] = 0.f; }
  __syncthreads();

  // x_proj[f][q4*16+i] -> P = exp(2*xp)   (step-invariant)
  float P[16];
  {
    float xp[16];
#pragma unroll
    for (int i = 0; i < 16; ++i) xp[i] = 0.f;
    for (int t = 0; t < 64; ++t) {
      float xv = inb[t*256 + f];
#pragma unroll
      for (int i4 = 0; i4 < 4; ++i4) {
        float4 w = *(const float4*)&s_buf[t*64 + q4*16 + i4*4];
        xp[i4*4+0] = fmaf(xv, w.x, xp[i4*4+0]);
        xp[i4*4+1] = fmaf(xv, w.y, xp[i4*4+1]);
        xp[i4*4+2] = fmaf(xv, w.z, xp[i4*4+2]);
        xp[i4*4+3] = fmaf(xv, w.w, xp[i4*4+3]);
      }
    }
#pragma unroll
    for (int i = 0; i < 16; ++i) P[i] = __expf(2.0f*xp[i]);
  }
  __syncthreads();  // done with We_x

  // eR -> LDS [j][257]
  for (int i = tid; i < 16384; i += 1024)
    s_buf[(i >> 8)*257 + (i & 255)] = eRg[i];

  float eKr[64];                       // eK[q4*64+ff][k=f]
#pragma unroll
  for (int ff = 0; ff < 64; ++ff) eKr[ff] = eKg[(q4*64 + ff)*256 + f];

  float wh[4], wsr[4];
#pragma unroll
  for (int jj = 0; jj < 4; ++jj) {
    wh[jj]  = aeW[(g16*4 + jj)*64 + u];         // We_h[j][u]
    wsr[jj] = aeW[(64 + g16*4 + jj)*64 + u];    // We_s[j][u]
  }
  const float aeb_u = aeb[u];
  const float eb_k  = ebg[f];
  float h_j = 0.f, c_j = 0.f;          // state for j = lane (per-wave copy)
  __syncthreads();

  // ================= encoder loop =================
  for (int t = 0; t < 64; ++t) {
    float xtv = inb[t*256 + f];
    if (t > 0) {  // LSTM update from z(t-1), redundant on all waves
      float gi = s_ag[lane], gf = s_ag[64+lane], gg = s_ag[128+lane], go = s_ag[192+lane];
      c_j = fmaf(gf, c_j, gi*gg);
      h_j = go * tanh_e(c_j);
      if (wv == 0) { s_h[lane] = h_j; s_xenc[(t-1)*68 + lane] = h_j; }
    }
    // A: E_u = exp(2*(h@We_h + c@We_s + b)[u])
    float p = 0.f;
#pragma unroll
    for (int jj = 0; jj < 4; ++jj) {
      float hh = __shfl(h_j, g16*4 + jj);
      float cc = __shfl(c_j, g16*4 + jj);
      p = fmaf(hh, wh[jj], p);
      p = fmaf(cc, wsr[jj], p);
    }
    p += __shfl_xor(p,1); p += __shfl_xor(p,2); p += __shfl_xor(p,4); p += __shfl_xor(p,8);
    float E = __expf(2.0f*(p + aeb_u));
    if (g16 == 0) s_hs[u] = E;
    __syncthreads();  // b1

    // C: scores via tanh=(EP-1)/(EP+1); softmax w/o max-sub; unnorm x_tilde
    float sc = 0.f;
#pragma unroll
    for (int i4 = 0; i4 < 4; ++i4) {
      float4 Ev = *(const float4*)&s_hs[q4*16 + i4*4];
      float4 vv = *(const float4*)&s_aev[q4*16 + i4*4];
      float w0 = Ev.x*P[i4*4+0], w1 = Ev.y*P[i4*4+1];
      float w2 = Ev.z*P[i4*4+2], w3 = Ev.w*P[i4*4+3];
      sc = fmaf((w0-1.f)*rcpf_(w0+1.f), vv.x, sc);
      sc = fmaf((w1-1.f)*rcpf_(w1+1.f), vv.y, sc);
      sc = fmaf((w2-1.f)*rcpf_(w2+1.f), vv.z, sc);
      sc = fmaf((w3-1.f)*rcpf_(w3+1.f), vv.w, sc);
    }
    sc += __shfl_xor(sc,1); sc += __shfl_xor(sc,2);
    float pe = __expf(sc);
    float ws = pe;
    ws += __shfl_xor(ws,4);  ws += __shfl_xor(ws,8);
    ws += __shfl_xor(ws,16); ws += __shfl_xor(ws,32);
    if (lane == 0) s_redB[wv] = ws;
    if (q4 == 0) s_xtld[f] = pe * xtv;
    __syncthreads();  // b2

    // z: (xtld.eK)*invS + h.eR + eb
    float4 r0 = *(const float4*)&s_redB[0];
    float4 r1 = *(const float4*)&s_redB[4];
    float4 r2 = *(const float4*)&s_redB[8];
    float4 r3 = *(const float4*)&s_redB[12];
    float S = ((r0.x+r0.y)+(r0.z+r0.w)) + ((r1.x+r1.y)+(r1.z+r1.w))
            + ((r2.x+r2.y)+(r2.z+r2.w)) + ((r3.x+r3.y)+(r3.z+r3.w));
    float invS = rcpf_(S);
    float pa = 0.f;
#pragma unroll
    for (int f4 = 0; f4 < 16; ++f4) {
      float4 xt = *(const float4*)&s_xtld[q4*64 + f4*4];
      pa = fmaf(xt.x, eKr[f4*4+0], pa);
      pa = fmaf(xt.y, eKr[f4*4+1], pa);
      pa = fmaf(xt.z, eKr[f4*4+2], pa);
      pa = fmaf(xt.w, eKr[f4*4+3], pa);
    }
    float ph = 0.f;
#pragma unroll
    for (int j4 = 0; j4 < 4; ++j4) {
      float4 hv = *(const float4*)&s_h[q4*16 + j4*4];
      ph = fmaf(hv.x, s_buf[(q4*16 + j4*4+0)*257 + f], ph);
      ph = fmaf(hv.y, s_buf[(q4*16 + j4*4+1)*257 + f], ph);
      ph = fmaf(hv.z, s_buf[(q4*16 + j4*4+2)*257 + f], ph);
      ph = fmaf(hv.w, s_buf[(q4*16 + j4*4+3)*257 + f], ph);
    }
    float v = fmaf(pa, invS, ph);
    v += __shfl_xor(v,1); v += __shfl_xor(v,2);
    v += eb_k;
    float a = ((f >> 6) == 2) ? tanh_e(v) : sigm(v);
    if (q4 == 0) s_ag[f] = a;
    __syncthreads();  // b3
  }
  // final encoder update -> xenc row 63
  {
    float gi = s_ag[lane], gf = s_ag[64+lane], gg = s_ag[128+lane], go = s_ag[192+lane];
    c_j = fmaf(gf, c_j, gi*gg);
    h_j = go * tanh_e(c_j);
    if (wv == 0) s_xenc[63*68 + lane] = h_j;
  }

  // ================= decoder prologue =================
  h_j = 0.f; c_j = 0.f;
  if (tid < 64) { s_h[tid] = 0.f; s_yprev[tid] = inb[tid*256 + 255]; s_fcb[tid] = fcb[tid]; }
  for (int i = tid; i < 4096; i += 1024) s_wx2[i] = adW[8192 + i];   // Wd_x
  __syncthreads();  // d1

  // pd = exp(2 * xe_proj[t'=u][g16*4+jj])   (step-invariant)
  float pd_[4];
  {
    float xe0 = 0.f, xe1 = 0.f, xe2 = 0.f, xe3 = 0.f;
    for (int e = 0; e < 64; ++e) {
      float xv = s_xenc[u*68 + e];
      float4 w = *(const float4*)&s_wx2[e*64 + g16*4];
      xe0 = fmaf(xv, w.x, xe0);
      xe1 = fmaf(xv, w.y, xe1);
      xe2 = fmaf(xv, w.z, xe2);
      xe3 = fmaf(xv, w.w, xe3);
    }
    pd_[0] = __expf(2.0f*xe0); pd_[1] = __expf(2.0f*xe1);
    pd_[2] = __expf(2.0f*xe2); pd_[3] = __expf(2.0f*xe3);
  }
  float dKr[64];
#pragma unroll
  for (int j = 0; j < 64; ++j) dKr[j] = dKg[j*256 + f];
  float wdd[4], wdc[4], advr[4];
#pragma unroll
  for (int jj = 0; jj < 4; ++jj) {
    wdd[jj]  = adW[(g16*4 + jj)*64 + u];
    wdc[jj]  = adW[(64 + g16*4 + jj)*64 + u];
    advr[jj] = adv[g16*4 + jj];
  }
  const float adb_u = adb[u];
  __syncthreads();  // d2: pd done with Wd_x
  for (int i = tid; i < 4160; i += 1024) s_wx2[i] = fcW[i];
  __syncthreads();  // d3: fcW staged

  // M1T[k=f][e] = sum_j fcW[e][j]*dK[j][k];  m2, mb folds
  for (int ee = 0; ee < 16; ++ee) {
    int e = q4*16 + ee;
    float acc = 0.f;
#pragma unroll
    for (int j4 = 0; j4 < 16; ++j4) {
      float4 w = *(const float4*)&s_wx2[e*64 + j4*4];
      acc = fmaf(w.x, dKr[j4*4+0], acc);
      acc = fmaf(w.y, dKr[j4*4+1], acc);
      acc = fmaf(w.z, dKr[j4*4+2], acc);
      acc = fmaf(w.w, dKr[j4*4+3], acc);
    }
    s_buf[f*68 + e] = acc;
  }
  float m2k = 0.f, mbk = dbg[f];
#pragma unroll
  for (int j4 = 0; j4 < 16; ++j4) {
    float4 w  = *(const float4*)&s_wx2[4096 + j4*4];   // fcW row 64
    float4 fb = *(const float4*)&s_fcb[j4*4];
    m2k = fmaf(w.x,  dKr[j4*4+0], m2k); m2k = fmaf(w.y,  dKr[j4*4+1], m2k);
    m2k = fmaf(w.z,  dKr[j4*4+2], m2k); m2k = fmaf(w.w,  dKr[j4*4+3], m2k);
    mbk = fmaf(fb.x, dKr[j4*4+0], mbk); mbk = fmaf(fb.y, dKr[j4*4+1], mbk);
    mbk = fmaf(fb.z, dKr[j4*4+2], mbk); mbk = fmaf(fb.w, dKr[j4*4+3], mbk);
  }
  __syncthreads();  // d4: M1T visible, fcW reads done

  // XMT[k=f][t] = sum_e xenc[t][e]*M1T[k][e]
  for (int tt = 0; tt < 16; ++tt) {
    int t = q4*16 + tt;
    float acc = 0.f;
#pragma unroll
    for (int e4 = 0; e4 < 16; ++e4) {
      float4 xv = *(const float4*)&s_xenc[t*68 + e4*4];
      float4 mv = *(const float4*)&s_buf[f*68 + e4*4];
      acc = fmaf(xv.x, mv.x, acc); acc = fmaf(xv.y, mv.y, acc);
      acc = fmaf(xv.z, mv.z, acc); acc = fmaf(xv.w, mv.w, acc);
    }
    s_wx2[f*68 + t] = acc;
  }
  __syncthreads();  // d5: XMT visible, M1T reads done

  // dR -> LDS [j][257]  (z(0) reads only after b1,b2 of step 0)
  for (int i = tid; i < 16384; i += 1024)
    s_buf[(i >> 8)*257 + (i & 255)] = dRg[i];

  // ================= decoder loop =================
  for (int t = 0; t < 64; ++t) {
    if (t > 0) {
      float gi = s_ag[lane], gf = s_ag[64+lane], gg = s_ag[128+lane], go = s_ag[192+lane];
      c_j = fmaf(gf, c_j, gi*gg);
      h_j = go * tanh_e(c_j);
      if (wv == 0) s_h[lane] = h_j;
    }
    float p = 0.f;
#pragma unroll
    for (int jj = 0; jj < 4; ++jj) {
      float hh = __shfl(h_j, g16*4 + jj);
      float cc = __shfl(c_j, g16*4 + jj);
      p = fmaf(hh, wdd[jj], p);
      p = fmaf(cc, wdc[jj], p);
    }
    p += __shfl_xor(p,1); p += __shfl_xor(p,2); p += __shfl_xor(p,4); p += __shfl_xor(p,8);
    float E = __expf(2.0f*(p + adb_u));
    if (g16 == 0) s_hs[u] = E;
    __syncthreads();  // b1

    // C: scores over t'=u, u-slice g16*4..+4
    float4 Ev = *(const float4*)&s_hs[g16*4];
    float w0 = Ev.x*pd_[0], w1 = Ev.y*pd_[1], w2 = Ev.z*pd_[2], w3 = Ev.w*pd_[3];
    float sc =        (w0-1.f)*rcpf_(w0+1.f) * advr[0];
    sc = fmaf((w1-1.f)*rcpf_(w1+1.f), advr[1], sc);
    sc = fmaf((w2-1.f)*rcpf_(w2+1.f), advr[2], sc);
    sc = fmaf((w3-1.f)*rcpf_(w3+1.f), advr[3], sc);
    sc += __shfl_xor(sc,1); sc += __shfl_xor(sc,2); sc += __shfl_xor(sc,4); sc += __shfl_xor(sc,8);
    float pe = __expf(sc);
    if (g16 == 0) s_pe[u] = pe;
    float ws = pe;
    ws += __shfl_xor(ws,16); ws += __shfl_xor(ws,32);
    if (lane == 0) s_redB[wv] = ws;
    __syncthreads();  // b2

    // z: invS*(pe.XMT) + d.dR + y*m2 + mb
    float4 r0 = *(const float4*)&s_redB[0];
    float4 r1 = *(const float4*)&s_redB[4];
    float4 r2 = *(const float4*)&s_redB[8];
    float4 r3 = *(const float4*)&s_redB[12];
    float S = ((r0.x+r0.y)+(r0.z+r0.w)) + ((r1.x+r1.y)+(r1.z+r1.w))
            + ((r2.x+r2.y)+(r2.z+r2.w)) + ((r3.x+r3.y)+(r3.z+r3.w));
    float invS = rcpf_(S);
    float pa1 = 0.f;
#pragma unroll
    for (int t4 = 0; t4 < 4; ++t4) {
      float4 pv = *(const float4*)&s_pe[q4*16 + t4*4];
      float4 xm = *(const float4*)&s_wx2[f*68 + q4*16 + t4*4];
      pa1 = fmaf(pv.x, xm.x, pa1); pa1 = fmaf(pv.y, xm.y, pa1);
      pa1 = fmaf(pv.z, xm.z, pa1); pa1 = fmaf(pv.w, xm.w, pa1);
    }
    float pa2 = 0.f;
#pragma unroll
    for (int j4 = 0; j4 < 4; ++j4) {
      float4 hv = *(const float4*)&s_h[q4*16 + j4*4];
      pa2 = fmaf(hv.x, s_buf[(q4*16 + j4*4+0)*257 + f], pa2);
      pa2 = fmaf(hv.y, s_buf[(q4*16 + j4*4+1)*257 + f], pa2);
      pa2 = fmaf(hv.z, s_buf[(q4*16 + j4*4+2)*257 + f], pa2);
      pa2 = fmaf(hv.w, s_buf[(q4*16 + j4*4+3)*257 + f], pa2);
    }
    float v = fmaf(pa1, invS, pa2);
    if (q4 == 0) v = fmaf(s_yprev[t], m2k, v + mbk);
    v += __shfl_xor(v,1); v += __shfl_xor(v,2);
    float a = ((f >> 6) == 2) ? tanh_e(v) : sigm(v);
    if (q4 == 0) s_ag[f] = a;
    __syncthreads();  // b3
  }
  // final decoder update -> d_n
  {
    float gi = s_ag[lane], gf = s_ag[64+lane], gg = s_ag[128+lane], go = s_ag[192+lane];
    c_j = fmaf(gf, c_j, gi*gg);
    h_j = go * tanh_e(c_j);
    if (wv == 0) s_h[lane] = h_j;
  }
  // final context from last step's pe/S
  {
    float4 r0 = *(const float4*)&s_redB[0];
    float4 r1 = *(const float4*)&s_redB[4];
    float4 r2 = *(const float4*)&s_redB[8];
    float4 r3 = *(const float4*)&s_redB[12];
    float S = ((r0.x+r0.y)+(r0.z+r0.w)) + ((r1.x+r1.y)+(r1.z+r1.w))
            + ((r2.x+r2.y)+(r2.z+r2.w)) + ((r3.x+r3.y)+(r3.z+r3.w));
    float invS = rcpf_(S);
    float pc = 0.f;
#pragma unroll
    for (int tt = 0; tt < 4; ++tt)
      pc = fmaf(s_pe[g16*4 + tt], s_xenc[(g16*4 + tt)*68 + u], pc);
    pc += __shfl_xor(pc,1); pc += __shfl_xor(pc,2); pc += __shfl_xor(pc,4); pc += __shfl_xor(pc,8);
    if (g16 == 0) s_ctx[u] = pc * invS;
  }
  __syncthreads();  // d6

  // epilogue: out = [d_n, ctx] @ fcfW + fcfb
  {
    const float* src = (q4 < 2) ? &s_h[q4*32] : &s_ctx[(q4-2)*32];
    float pa = 0.f;
#pragma unroll
    for (int i4 = 0; i4 < 8; ++i4) {
      float4 vv = *(const float4*)&src[i4*4];
      int row = q4*32 + i4*4;
      pa = fmaf(vv.x, fcfW[(row+0)*256 + f], pa);
      pa = fmaf(vv.y, fcfW[(row+1)*256 + f], pa);
      pa = fmaf(vv.z, fcfW[(row+2)*256 + f], pa);
      pa = fmaf(vv.w, fcfW[(row+3)*256 + f], pa);
    }
    pa += __shfl_xor(pa,1); pa += __shfl_xor(pa,2);
    if (q4 == 0) out[b*256 + f] = pa + fcfb[f];
  }
}

extern "C" void kernel_launch(void* const* d_in, const int* in_sizes, int n_in,
                              void* d_out, int out_size, void* d_ws, size_t ws_size,
                              hipStream_t stream) {
  const float* gin  = (const float*)d_in[0];
  const float* eK   = (const float*)d_in[1];
  const float* eR   = (const float*)d_in[2];
  const float* eb   = (const float*)d_in[3];
  const float* dK   = (const float*)d_in[4];
  const float* dR   = (const float*)d_in[5];
  const float* db   = (const float*)d_in[6];
  const float* aeW  = (const float*)d_in[7];
  const float* aeb  = (const float*)d_in[8];
  const float* aev  = (const float*)d_in[9];
  // d_in[10] attn_e_vb, d_in[14] attn_d_vb: constant shifts, cancel in softmax
  const float* adW  = (const float*)d_in[11];
  const float* adb  = (const float*)d_in[12];
  const float* adv  = (const float*)d_in[13];
  const float* fcW  = (const float*)d_in[15];
  const float* fcb  = (const float*)d_in[16];
  const float* fcfW = (const float*)d_in[17];
  const float* fcfb = (const float*)d_in[18];
  float* out = (float*)d_out;

  const int B = in_sizes[0] / (64*256);
  hipLaunchKernelGGL(darnn_fused, dim3(B), dim3(1024), 0, stream,
                     gin, eK, eR, eb, dK, dR, db, aeW, aeb, aev,
                     adW, adb, adv, fcW, fcb, fcfW, fcfb, out);
}

// Round 4
// 511.819 us; speedup vs baseline: 2.1962x; 2.1962x over previous
//
#include <hip/hip_runtime.h>
#include <math.h>

#define ALIGN16 __attribute__((aligned(16)))

__device__ __forceinline__ float rcpf_(float x){ return __builtin_amdgcn_rcpf(x); }
__device__ __forceinline__ float tanh_e(float x){
  float t = __expf(2.0f*x);
  return (t - 1.0f) * rcpf_(t + 1.0f);
}
__device__ __forceinline__ float sigm(float x){
  return rcpf_(1.0f + __expf(-x));
}

// 512 threads (8 waves, 2/SIMD) per batch element; 256 blocks, 1 per CU.
// __launch_bounds__(512,2) -> 256 VGPR budget: eKr[128]+P[32] fit, NO spills.
// LSTM state (h,c) register-resident per lane (j=lane), redundantly updated
// by all 8 waves -> no serial phase; 3 barriers/step in both loops.
// Roles: A-phase (u8=tid>>3, grp=tid&7); C/z phases (f=tid>>1, half=tid&1).
// Decoder fc layer folded via XM_t[t][k] = sum_e xenc[t][e]*(fcW_ctx@dK)[e][k].
__global__ __launch_bounds__(512, 2)
void darnn_fused(const float* __restrict__ gin,   // [256][64][256]
                 const float* __restrict__ eKg,   // [256][256]
                 const float* __restrict__ eRg,   // [64][256]
                 const float* __restrict__ ebg,   // [256]
                 const float* __restrict__ dKg,   // [64][256]
                 const float* __restrict__ dRg,   // [64][256]
                 const float* __restrict__ dbg,   // [256]
                 const float* __restrict__ aeW,   // [192][64]
                 const float* __restrict__ aeb,   // [64]
                 const float* __restrict__ aev,   // [64]
                 const float* __restrict__ adW,   // [192][64]
                 const float* __restrict__ adb,   // [64]
                 const float* __restrict__ adv,   // [64]
                 const float* __restrict__ fcW,   // [65][64]
                 const float* __restrict__ fcb,   // [64]
                 const float* __restrict__ fcfW,  // [128][256]
                 const float* __restrict__ fcfb,  // [256]
                 float* __restrict__ out)         // [256][256]
{
  __shared__ ALIGN16 float s_buf[17408];   // We_x -> eR[64][257] -> M1T[256][68] -> dR[64][257]
  __shared__ ALIGN16 float s_wx2[16448];   // Wd_x -> fcW(4160) -> XM_t[64][257]
  __shared__ ALIGN16 float s_xenc[64*68];  // x_encoded
  __shared__ ALIGN16 float s_ag[256];      // activated gates
  __shared__ ALIGN16 float s_xtld[256];    // unnormalized x_tilde
  __shared__ ALIGN16 float s_hs[64];       // E_u = exp(2*preact_u)
  __shared__ ALIGN16 float s_pe[64];       // decoder unnorm softmax
  __shared__ ALIGN16 float s_redB[8];      // per-wave softmax partials
  __shared__ ALIGN16 float s_ctx[64];
  __shared__ ALIGN16 float s_yprev[64];
  __shared__ ALIGN16 float s_fcb[64];
  __shared__ ALIGN16 float s_h[64];        // h (enc) / d (dec) for z-phase
  __shared__ ALIGN16 float s_aev[64];

  const int tid  = threadIdx.x;
  const int lane = tid & 63;
  const int wv   = tid >> 6;   // 0..7
  const int f    = tid >> 1;   // 0..255
  const int half = tid & 1;
  const int u8   = tid >> 3;   // 0..63
  const int grp  = tid & 7;
  const int b    = blockIdx.x;
  const float* inb = gin + (size_t)b * (64*256);

  // ================= encoder prologue =================
  for (int i = tid; i < 4096; i += 512) s_buf[i] = aeW[8192 + i];   // We_x
  if (tid < 64) { s_aev[tid] = aev[tid]; s_h[tid] = 0.f; }
  __syncthreads();

  // x_proj[f][half*32+i] -> P = exp(2*xp)  (step-invariant)
  float P[32];
  {
#pragma unroll
    for (int i = 0; i < 32; ++i) P[i] = 0.f;
    for (int t = 0; t < 64; ++t) {
      float xv = inb[t*256 + f];
#pragma unroll
      for (int i4 = 0; i4 < 8; ++i4) {
        float4 w = *(const float4*)&s_buf[t*64 + half*32 + i4*4];
        P[i4*4+0] = fmaf(xv, w.x, P[i4*4+0]);
        P[i4*4+1] = fmaf(xv, w.y, P[i4*4+1]);
        P[i4*4+2] = fmaf(xv, w.z, P[i4*4+2]);
        P[i4*4+3] = fmaf(xv, w.w, P[i4*4+3]);
      }
    }
#pragma unroll
    for (int i = 0; i < 32; ++i) P[i] = __expf(2.0f*P[i]);
  }
  float vsum = 0.f;   // sum of aev over this half's slice
#pragma unroll
  for (int i4 = 0; i4 < 8; ++i4) {
    float4 vv = *(const float4*)&s_aev[half*32 + i4*4];
    vsum += (vv.x + vv.y) + (vv.z + vv.w);
  }
  __syncthreads();  // We_x dead

  // eR -> LDS [j][257] (z reads are lane-consecutive, conflict-free)
  for (int i = tid; i < 16384; i += 512)
    s_buf[(i >> 8)*257 + (i & 255)] = eRg[i];
  float eKr[128];
#pragma unroll
  for (int q = 0; q < 128; ++q) eKr[q] = eKg[(half*128 + q)*256 + f];
  float wh[8], wsr[8];
#pragma unroll
  for (int jj = 0; jj < 8; ++jj) {
    wh[jj]  = aeW[(grp*8+jj)*64 + u8];        // We_h[j][u8]
    wsr[jj] = aeW[(64+grp*8+jj)*64 + u8];     // We_s[j][u8]
  }
  const float aeb_u = aeb[u8];
  const float eb_k  = ebg[f];
  float h_j = 0.f, c_j = 0.f;   // per-wave redundant state, j = lane
  __syncthreads();

  // ================= encoder loop (3 barriers/step) =================
  for (int t = 0; t < 64; ++t) {
    if (t > 0) {  // LSTM update from z(t-1), redundant on all waves
      float gi = s_ag[lane], gf = s_ag[64+lane], gg = s_ag[128+lane], go = s_ag[192+lane];
      c_j = fmaf(gf, c_j, gi*gg);
      h_j = go * tanh_e(c_j);
      if (wv == 0) { s_h[lane] = h_j; s_xenc[(t-1)*68 + lane] = h_j; }
    }
    float xtv = inb[t*256 + f];
    // A: E_u = exp(2*(h@We_h + c@We_s + b)[u])
    float p = 0.f;
#pragma unroll
    for (int jj = 0; jj < 8; ++jj) {
      float hh = __shfl(h_j, grp*8 + jj);
      float cc = __shfl(c_j, grp*8 + jj);
      p = fmaf(hh, wh[jj], p);
      p = fmaf(cc, wsr[jj], p);
    }
    p += __shfl_xor(p,1); p += __shfl_xor(p,2); p += __shfl_xor(p,4);
    float E = __expf(2.0f*(p + aeb_u));
    if (grp == 0) s_hs[u8] = E;
    __syncthreads();  // b1

    // C: sc = sum v*tanh = vsum - 2*sum v*rcp(E*P+1); softmax w/o max-sub
    float sacc = 0.f;
#pragma unroll
    for (int i4 = 0; i4 < 8; ++i4) {
      float4 Ev = *(const float4*)&s_hs[half*32 + i4*4];
      float4 vv = *(const float4*)&s_aev[half*32 + i4*4];
      sacc = fmaf(vv.x, rcpf_(fmaf(Ev.x, P[i4*4+0], 1.f)), sacc);
      sacc = fmaf(vv.y, rcpf_(fmaf(Ev.y, P[i4*4+1], 1.f)), sacc);
      sacc = fmaf(vv.z, rcpf_(fmaf(Ev.z, P[i4*4+2], 1.f)), sacc);
      sacc = fmaf(vv.w, rcpf_(fmaf(Ev.w, P[i4*4+3], 1.f)), sacc);
    }
    float sc = fmaf(-2.f, sacc, vsum);
    sc += __shfl_xor(sc, 1);
    float pe = __expf(sc);
    float ws = pe;   // per-wave sum over 32 distinct f (skip xor1: halves equal)
    ws += __shfl_xor(ws,2); ws += __shfl_xor(ws,4);
    ws += __shfl_xor(ws,8); ws += __shfl_xor(ws,16); ws += __shfl_xor(ws,32);
    if (lane == 0) s_redB[wv] = ws;
    if (half == 0) s_xtld[f] = pe * xtv;     // unnormalized
    __syncthreads();  // b2

    // z: (xtld.eK)*invS + h.eR + eb
    float4 r0 = *(const float4*)&s_redB[0];
    float4 r1 = *(const float4*)&s_redB[4];
    float invS = rcpf_(((r0.x+r0.y)+(r0.z+r0.w)) + ((r1.x+r1.y)+(r1.z+r1.w)));
    float pa = 0.f;
#pragma unroll
    for (int q4 = 0; q4 < 32; ++q4) {
      float4 xt = *(const float4*)&s_xtld[half*128 + q4*4];
      pa = fmaf(xt.x, eKr[q4*4+0], pa);
      pa = fmaf(xt.y, eKr[q4*4+1], pa);
      pa = fmaf(xt.z, eKr[q4*4+2], pa);
      pa = fmaf(xt.w, eKr[q4*4+3], pa);
    }
    float ph = 0.f;
#pragma unroll
    for (int jj = 0; jj < 32; ++jj)
      ph = fmaf(s_h[half*32+jj], s_buf[(half*32+jj)*257 + f], ph);
    float v = fmaf(pa, invS, ph);
    v += __shfl_xor(v, 1);
    v += eb_k;
    float a = ((f >> 6) == 2) ? tanh_e(v) : sigm(v);
    if (half == 0) s_ag[f] = a;
    __syncthreads();  // b3
  }
  // final encoder update -> xenc row 63
  {
    float gi = s_ag[lane], gf = s_ag[64+lane], gg = s_ag[128+lane], go = s_ag[192+lane];
    c_j = fmaf(gf, c_j, gi*gg);
    h_j = go * tanh_e(c_j);
    if (wv == 0) s_xenc[63*68 + lane] = h_j;
  }

  // ================= decoder prologue =================
  h_j = 0.f; c_j = 0.f;
  if (tid < 64) { s_h[tid] = 0.f; s_yprev[tid] = inb[tid*256 + 255]; s_fcb[tid] = fcb[tid]; }
  for (int i = tid; i < 4096; i += 512) s_wx2[i] = adW[8192 + i];   // Wd_x
  __syncthreads();  // d1

  // pd = exp(2 * xe_proj[t'=u8][grp*8+q])  (step-invariant)
  float pd_[8];
  {
    float xe[8];
#pragma unroll
    for (int q = 0; q < 8; ++q) xe[q] = 0.f;
    for (int e = 0; e < 64; ++e) {
      float xv = s_xenc[u8*68 + e];
      float4 w0 = *(const float4*)&s_wx2[e*64 + grp*8];
      float4 w1 = *(const float4*)&s_wx2[e*64 + grp*8 + 4];
      xe[0]=fmaf(xv,w0.x,xe[0]); xe[1]=fmaf(xv,w0.y,xe[1]);
      xe[2]=fmaf(xv,w0.z,xe[2]); xe[3]=fmaf(xv,w0.w,xe[3]);
      xe[4]=fmaf(xv,w1.x,xe[4]); xe[5]=fmaf(xv,w1.y,xe[5]);
      xe[6]=fmaf(xv,w1.z,xe[6]); xe[7]=fmaf(xv,w1.w,xe[7]);
    }
#pragma unroll
    for (int q = 0; q < 8; ++q) pd_[q] = __expf(2.0f*xe[q]);
  }
  float dKr[64];
#pragma unroll
  for (int j = 0; j < 64; ++j) dKr[j] = dKg[j*256 + f];
  float wdd[8], wdc[8], advr[8];
  float vsum_d = 0.f;
#pragma unroll
  for (int jj = 0; jj < 8; ++jj) {
    wdd[jj]  = adW[(grp*8+jj)*64 + u8];
    wdc[jj]  = adW[(64+grp*8+jj)*64 + u8];
    advr[jj] = adv[grp*8+jj];
    vsum_d += advr[jj];
  }
  const float adb_u = adb[u8];
  __syncthreads();  // d2: Wd_x dead
  for (int i = tid; i < 4160; i += 512) s_wx2[i] = fcW[i];
  __syncthreads();  // d3

  // M1T[k=f][e] = sum_j fcW[e][j]*dK[j][k]
  for (int ee = 0; ee < 32; ++ee) {
    int e = half*32 + ee;
    float acc = 0.f;
#pragma unroll
    for (int j4 = 0; j4 < 16; ++j4) {
      float4 w = *(const float4*)&s_wx2[e*64 + j4*4];
      acc = fmaf(w.x, dKr[j4*4+0], acc);
      acc = fmaf(w.y, dKr[j4*4+1], acc);
      acc = fmaf(w.z, dKr[j4*4+2], acc);
      acc = fmaf(w.w, dKr[j4*4+3], acc);
    }
    s_buf[f*68 + e] = acc;
  }
  float m2k = 0.f, mbk = dbg[f];
#pragma unroll
  for (int j4 = 0; j4 < 16; ++j4) {
    float4 w  = *(const float4*)&s_wx2[4096 + j4*4];   // fcW row 64
    float4 fb = *(const float4*)&s_fcb[j4*4];
    m2k = fmaf(w.x,  dKr[j4*4+0], m2k); m2k = fmaf(w.y,  dKr[j4*4+1], m2k);
    m2k = fmaf(w.z,  dKr[j4*4+2], m2k); m2k = fmaf(w.w,  dKr[j4*4+3], m2k);
    mbk = fmaf(fb.x, dKr[j4*4+0], mbk); mbk = fmaf(fb.y, dKr[j4*4+1], mbk);
    mbk = fmaf(fb.z, dKr[j4*4+2], mbk); mbk = fmaf(fb.w, dKr[j4*4+3], mbk);
  }
  __syncthreads();  // d4: M1T visible; fcW reads done

  // XM_t[t][k=f] = sum_e xenc[t][e]*M1T[k][e]
  for (int tt = 0; tt < 32; ++tt) {
    int t = half*32 + tt;
    float acc = 0.f;
#pragma unroll
    for (int e4 = 0; e4 < 16; ++e4) {
      float4 xv = *(const float4*)&s_xenc[t*68 + e4*4];
      float4 mv = *(const float4*)&s_buf[f*68 + e4*4];
      acc = fmaf(xv.x, mv.x, acc); acc = fmaf(xv.y, mv.y, acc);
      acc = fmaf(xv.z, mv.z, acc); acc = fmaf(xv.w, mv.w, acc);
    }
    s_wx2[t*257 + f] = acc;
  }
  __syncthreads();  // d5: XM_t visible; M1T reads done

  // dR -> LDS [j][257] (first z read is after b1+b2 of step 0)
  for (int i = tid; i < 16384; i += 512)
    s_buf[(i >> 8)*257 + (i & 255)] = dRg[i];

  // ================= decoder loop (3 barriers/step) =================
  for (int t = 0; t < 64; ++t) {
    if (t > 0) {
      float gi = s_ag[lane], gf = s_ag[64+lane], gg = s_ag[128+lane], go = s_ag[192+lane];
      c_j = fmaf(gf, c_j, gi*gg);
      h_j = go * tanh_e(c_j);
      if (wv == 0) s_h[lane] = h_j;
    }
    // A: E_u
    float p = 0.f;
#pragma unroll
    for (int jj = 0; jj < 8; ++jj) {
      float hh = __shfl(h_j, grp*8 + jj);
      float cc = __shfl(c_j, grp*8 + jj);
      p = fmaf(hh, wdd[jj], p);
      p = fmaf(cc, wdc[jj], p);
    }
    p += __shfl_xor(p,1); p += __shfl_xor(p,2); p += __shfl_xor(p,4);
    float E = __expf(2.0f*(p + adb_u));
    if (grp == 0) s_hs[u8] = E;
    __syncthreads();  // b1

    // C: t'=u8, u-slice grp*8+[0,8)
    float4 E0 = *(const float4*)&s_hs[grp*8];
    float4 E1 = *(const float4*)&s_hs[grp*8+4];
    float sacc = 0.f;
    sacc = fmaf(advr[0], rcpf_(fmaf(E0.x, pd_[0], 1.f)), sacc);
    sacc = fmaf(advr[1], rcpf_(fmaf(E0.y, pd_[1], 1.f)), sacc);
    sacc = fmaf(advr[2], rcpf_(fmaf(E0.z, pd_[2], 1.f)), sacc);
    sacc = fmaf(advr[3], rcpf_(fmaf(E0.w, pd_[3], 1.f)), sacc);
    sacc = fmaf(advr[4], rcpf_(fmaf(E1.x, pd_[4], 1.f)), sacc);
    sacc = fmaf(advr[5], rcpf_(fmaf(E1.y, pd_[5], 1.f)), sacc);
    sacc = fmaf(advr[6], rcpf_(fmaf(E1.z, pd_[6], 1.f)), sacc);
    sacc = fmaf(advr[7], rcpf_(fmaf(E1.w, pd_[7], 1.f)), sacc);
    float sc = fmaf(-2.f, sacc, vsum_d);
    sc += __shfl_xor(sc,1); sc += __shfl_xor(sc,2); sc += __shfl_xor(sc,4);
    float pe = __expf(sc);
    if (grp == 0) s_pe[u8] = pe;
    float ws = pe;   // sum over the wave's 8 distinct t'
    ws += __shfl_xor(ws,8); ws += __shfl_xor(ws,16); ws += __shfl_xor(ws,32);
    if (lane == 0) s_redB[wv] = ws;
    __syncthreads();  // b2

    // z: invS*(pe.XM_t) + d.dR + y*m2 + mb
    float4 r0 = *(const float4*)&s_redB[0];
    float4 r1 = *(const float4*)&s_redB[4];
    float invS = rcpf_(((r0.x+r0.y)+(r0.z+r0.w)) + ((r1.x+r1.y)+(r1.z+r1.w)));
    float pa1 = 0.f;
#pragma unroll
    for (int tt = 0; tt < 32; ++tt)
      pa1 = fmaf(s_pe[half*32+tt], s_wx2[(half*32+tt)*257 + f], pa1);
    float pa2 = 0.f;
#pragma unroll
    for (int jj = 0; jj < 32; ++jj)
      pa2 = fmaf(s_h[half*32+jj], s_buf[(half*32+jj)*257 + f], pa2);
    float v = fmaf(pa1, invS, pa2);
    if (half == 0) v = fmaf(s_yprev[t], m2k, v + mbk);
    v += __shfl_xor(v, 1);
    float a = ((f >> 6) == 2) ? tanh_e(v) : sigm(v);
    if (half == 0) s_ag[f] = a;
    __syncthreads();  // b3
  }
  // final decoder update -> d_n
  {
    float gi = s_ag[lane], gf = s_ag[64+lane], gg = s_ag[128+lane], go = s_ag[192+lane];
    c_j = fmaf(gf, c_j, gi*gg);
    h_j = go * tanh_e(c_j);
    if (wv == 0) s_h[lane] = h_j;
  }
  // final context from last step's pe/S
  {
    float4 r0 = *(const float4*)&s_redB[0];
    float4 r1 = *(const float4*)&s_redB[4];
    float invS = rcpf_(((r0.x+r0.y)+(r0.z+r0.w)) + ((r1.x+r1.y)+(r1.z+r1.w)));
    float pc = 0.f;
#pragma unroll
    for (int q = 0; q < 8; ++q)
      pc = fmaf(s_pe[grp*8+q], s_xenc[(grp*8+q)*68 + u8], pc);
    pc += __shfl_xor(pc,1); pc += __shfl_xor(pc,2); pc += __shfl_xor(pc,4);
    if (grp == 0) s_ctx[u8] = pc * invS;
  }
  __syncthreads();  // d6

  // epilogue: out = [d_n, ctx] @ fcfW + fcfb
  {
    const float* fw  = fcfW + (size_t)(half*64)*256 + f;
    const float* src = half ? s_ctx : s_h;
    float pa = 0.f;
#pragma unroll
    for (int j = 0; j < 64; ++j)
      pa = fmaf(src[j], fw[(size_t)j*256], pa);
    pa += __shfl_xor(pa, 1);
    if (half == 0) out[b*256 + f] = pa + fcfb[f];
  }
}

extern "C" void kernel_launch(void* const* d_in, const int* in_sizes, int n_in,
                              void* d_out, int out_size, void* d_ws, size_t ws_size,
                              hipStream_t stream) {
  const float* gin  = (const float*)d_in[0];
  const float* eK   = (const float*)d_in[1];
  const float* eR   = (const float*)d_in[2];
  const float* eb   = (const float*)d_in[3];
  const float* dK   = (const float*)d_in[4];
  const float* dR   = (const float*)d_in[5];
  const float* db   = (const float*)d_in[6];
  const float* aeW  = (const float*)d_in[7];
  const float* aeb  = (const float*)d_in[8];
  const float* aev  = (const float*)d_in[9];
  // d_in[10] attn_e_vb, d_in[14] attn_d_vb: constant shifts, cancel in softmax
  const float* adW  = (const float*)d_in[11];
  const float* adb  = (const float*)d_in[12];
  const float* adv  = (const float*)d_in[13];
  const float* fcW  = (const float*)d_in[15];
  const float* fcb  = (const float*)d_in[16];
  const float* fcfW = (const float*)d_in[17];
  const float* fcfb = (const float*)d_in[18];
  float* out = (float*)d_out;

  const int B = in_sizes[0] / (64*256);
  hipLaunchKernelGGL(darnn_fused, dim3(B), dim3(512), 0, stream,
                     gin, eK, eR, eb, dK, dR, db, aeW, aeb, aev,
                     adW, adb, adv, fcW, fcb, fcfW, fcfb, out);
}

// Round 5
// 510.495 us; speedup vs baseline: 2.2019x; 1.0026x over previous
//
#include <hip/hip_runtime.h>
#include <math.h>

#define ALIGN16 __attribute__((aligned(16)))

__device__ __forceinline__ float rcpf_(float x){ return __builtin_amdgcn_rcpf(x); }
__device__ __forceinline__ float tanh_e(float x){
  float t = __expf(2.0f*x);
  return (t - 1.0f) * rcpf_(t + 1.0f);
}
__device__ __forceinline__ float sigm(float x){
  return rcpf_(1.0f + __expf(-x));
}

// 512 threads (8 waves, 2/SIMD) per batch element; 256 blocks, 1 per CU.
// amdgpu_waves_per_eu(2,2): EXACTLY 2 waves/SIMD -> 256-VGPR budget.
// (launch_bounds 2nd arg proved to mean min BLOCKS/CU on this toolchain:
//  R3 (1024,4)->64 VGPR, R4 (512,2)->128 VGPR, both spilled. This attribute
//  is the unambiguous control.)
// LSTM state (h,c) register-resident per lane (j=lane), redundantly updated
// by all 8 waves -> no serial phase; 3 barriers/step in both loops.
// Roles: A-phase (u8=tid>>3, grp=tid&7); C/z phases (f=tid>>1, half=tid&1).
// Decoder fc layer folded via XM_t[t][k] = sum_e xenc[t][e]*(fcW_ctx@dK)[e][k].
__global__ __attribute__((amdgpu_waves_per_eu(2, 2))) __launch_bounds__(512)
void darnn_fused(const float* __restrict__ gin,   // [256][64][256]
                 const float* __restrict__ eKg,   // [256][256]
                 const float* __restrict__ eRg,   // [64][256]
                 const float* __restrict__ ebg,   // [256]
                 const float* __restrict__ dKg,   // [64][256]
                 const float* __restrict__ dRg,   // [64][256]
                 const float* __restrict__ dbg,   // [256]
                 const float* __restrict__ aeW,   // [192][64]
                 const float* __restrict__ aeb,   // [64]
                 const float* __restrict__ aev,   // [64]
                 const float* __restrict__ adW,   // [192][64]
                 const float* __restrict__ adb,   // [64]
                 const float* __restrict__ adv,   // [64]
                 const float* __restrict__ fcW,   // [65][64]
                 const float* __restrict__ fcb,   // [64]
                 const float* __restrict__ fcfW,  // [128][256]
                 const float* __restrict__ fcfb,  // [256]
                 float* __restrict__ out)         // [256][256]
{
  __shared__ ALIGN16 float s_buf[17408];   // We_x -> eR[64][257] -> M1T[256][68] -> dR[64][257]
  __shared__ ALIGN16 float s_wx2[16448];   // Wd_x -> fcW(4160) -> XM_t[64][257]
  __shared__ ALIGN16 float s_xenc[64*68];  // x_encoded
  __shared__ ALIGN16 float s_ag[256];      // activated gates
  __shared__ ALIGN16 float s_xtld[256];    // unnormalized x_tilde
  __shared__ ALIGN16 float s_hs[64];       // E_u = exp(2*preact_u)
  __shared__ ALIGN16 float s_pe[64];       // decoder unnorm softmax
  __shared__ ALIGN16 float s_redB[8];      // per-wave softmax partials
  __shared__ ALIGN16 float s_ctx[64];
  __shared__ ALIGN16 float s_yprev[64];
  __shared__ ALIGN16 float s_fcb[64];
  __shared__ ALIGN16 float s_h[64];        // h (enc) / d (dec) for z-phase
  __shared__ ALIGN16 float s_aev[64];

  const int tid  = threadIdx.x;
  const int lane = tid & 63;
  const int wv   = tid >> 6;   // 0..7
  const int f    = tid >> 1;   // 0..255
  const int half = tid & 1;
  const int u8   = tid >> 3;   // 0..63
  const int grp  = tid & 7;
  const int b    = blockIdx.x;
  const float* inb = gin + (size_t)b * (64*256);

  // ================= encoder prologue =================
  for (int i = tid; i < 4096; i += 512) s_buf[i] = aeW[8192 + i];   // We_x
  if (tid < 64) { s_aev[tid] = aev[tid]; s_h[tid] = 0.f; }
  __syncthreads();

  // x_proj[f][half*32+i] -> P = exp(2*xp)  (step-invariant)
  float P[32];
  {
#pragma unroll
    for (int i = 0; i < 32; ++i) P[i] = 0.f;
    for (int t = 0; t < 64; ++t) {
      float xv = inb[t*256 + f];
#pragma unroll
      for (int i4 = 0; i4 < 8; ++i4) {
        float4 w = *(const float4*)&s_buf[t*64 + half*32 + i4*4];
        P[i4*4+0] = fmaf(xv, w.x, P[i4*4+0]);
        P[i4*4+1] = fmaf(xv, w.y, P[i4*4+1]);
        P[i4*4+2] = fmaf(xv, w.z, P[i4*4+2]);
        P[i4*4+3] = fmaf(xv, w.w, P[i4*4+3]);
      }
    }
#pragma unroll
    for (int i = 0; i < 32; ++i) P[i] = __expf(2.0f*P[i]);
  }
  float vsum = 0.f;   // sum of aev over this half's slice
#pragma unroll
  for (int i4 = 0; i4 < 8; ++i4) {
    float4 vv = *(const float4*)&s_aev[half*32 + i4*4];
    vsum += (vv.x + vv.y) + (vv.z + vv.w);
  }
  __syncthreads();  // We_x dead

  // eR -> LDS [j][257] (z reads are lane-consecutive, conflict-free)
  for (int i = tid; i < 16384; i += 512)
    s_buf[(i >> 8)*257 + (i & 255)] = eRg[i];
  float eKr[128];
#pragma unroll
  for (int q = 0; q < 128; ++q) eKr[q] = eKg[(half*128 + q)*256 + f];
  float wh[8], wsr[8];
#pragma unroll
  for (int jj = 0; jj < 8; ++jj) {
    wh[jj]  = aeW[(grp*8+jj)*64 + u8];        // We_h[j][u8]
    wsr[jj] = aeW[(64+grp*8+jj)*64 + u8];     // We_s[j][u8]
  }
  const float aeb_u = aeb[u8];
  const float eb_k  = ebg[f];
  float h_j = 0.f, c_j = 0.f;   // per-wave redundant state, j = lane
  __syncthreads();

  // ================= encoder loop (3 barriers/step) =================
  for (int t = 0; t < 64; ++t) {
    if (t > 0) {  // LSTM update from z(t-1), redundant on all waves
      float gi = s_ag[lane], gf = s_ag[64+lane], gg = s_ag[128+lane], go = s_ag[192+lane];
      c_j = fmaf(gf, c_j, gi*gg);
      h_j = go * tanh_e(c_j);
      if (wv == 0) { s_h[lane] = h_j; s_xenc[(t-1)*68 + lane] = h_j; }
    }
    float xtv = inb[t*256 + f];
    // A: E_u = exp(2*(h@We_h + c@We_s + b)[u])
    float p = 0.f;
#pragma unroll
    for (int jj = 0; jj < 8; ++jj) {
      float hh = __shfl(h_j, grp*8 + jj);
      float cc = __shfl(c_j, grp*8 + jj);
      p = fmaf(hh, wh[jj], p);
      p = fmaf(cc, wsr[jj], p);
    }
    p += __shfl_xor(p,1); p += __shfl_xor(p,2); p += __shfl_xor(p,4);
    float E = __expf(2.0f*(p + aeb_u));
    if (grp == 0) s_hs[u8] = E;
    __syncthreads();  // b1

    // C: sc = sum v*tanh = vsum - 2*sum v*rcp(E*P+1); softmax w/o max-sub
    float sacc = 0.f;
#pragma unroll
    for (int i4 = 0; i4 < 8; ++i4) {
      float4 Ev = *(const float4*)&s_hs[half*32 + i4*4];
      float4 vv = *(const float4*)&s_aev[half*32 + i4*4];
      sacc = fmaf(vv.x, rcpf_(fmaf(Ev.x, P[i4*4+0], 1.f)), sacc);
      sacc = fmaf(vv.y, rcpf_(fmaf(Ev.y, P[i4*4+1], 1.f)), sacc);
      sacc = fmaf(vv.z, rcpf_(fmaf(Ev.z, P[i4*4+2], 1.f)), sacc);
      sacc = fmaf(vv.w, rcpf_(fmaf(Ev.w, P[i4*4+3], 1.f)), sacc);
    }
    float sc = fmaf(-2.f, sacc, vsum);
    sc += __shfl_xor(sc, 1);
    float pe = __expf(sc);
    float ws = pe;   // per-wave sum over 32 distinct f (skip xor1: halves equal)
    ws += __shfl_xor(ws,2); ws += __shfl_xor(ws,4);
    ws += __shfl_xor(ws,8); ws += __shfl_xor(ws,16); ws += __shfl_xor(ws,32);
    if (lane == 0) s_redB[wv] = ws;
    if (half == 0) s_xtld[f] = pe * xtv;     // unnormalized
    __syncthreads();  // b2

    // z: (xtld.eK)*invS + h.eR + eb
    float4 r0 = *(const float4*)&s_redB[0];
    float4 r1 = *(const float4*)&s_redB[4];
    float invS = rcpf_(((r0.x+r0.y)+(r0.z+r0.w)) + ((r1.x+r1.y)+(r1.z+r1.w)));
    float pa = 0.f;
#pragma unroll
    for (int q4 = 0; q4 < 32; ++q4) {
      float4 xt = *(const float4*)&s_xtld[half*128 + q4*4];
      pa = fmaf(xt.x, eKr[q4*4+0], pa);
      pa = fmaf(xt.y, eKr[q4*4+1], pa);
      pa = fmaf(xt.z, eKr[q4*4+2], pa);
      pa = fmaf(xt.w, eKr[q4*4+3], pa);
    }
    float ph = 0.f;
#pragma unroll
    for (int jj = 0; jj < 32; ++jj)
      ph = fmaf(s_h[half*32+jj], s_buf[(half*32+jj)*257 + f], ph);
    float v = fmaf(pa, invS, ph);
    v += __shfl_xor(v, 1);
    v += eb_k;
    float a = ((f >> 6) == 2) ? tanh_e(v) : sigm(v);
    if (half == 0) s_ag[f] = a;
    __syncthreads();  // b3
  }
  // final encoder update -> xenc row 63
  {
    float gi = s_ag[lane], gf = s_ag[64+lane], gg = s_ag[128+lane], go = s_ag[192+lane];
    c_j = fmaf(gf, c_j, gi*gg);
    h_j = go * tanh_e(c_j);
    if (wv == 0) s_xenc[63*68 + lane] = h_j;
  }

  // ================= decoder prologue =================
  h_j = 0.f; c_j = 0.f;
  if (tid < 64) { s_h[tid] = 0.f; s_yprev[tid] = inb[tid*256 + 255]; s_fcb[tid] = fcb[tid]; }
  for (int i = tid; i < 4096; i += 512) s_wx2[i] = adW[8192 + i];   // Wd_x
  __syncthreads();  // d1

  // pd = exp(2 * xe_proj[t'=u8][grp*8+q])  (step-invariant)
  float pd_[8];
  {
    float xe[8];
#pragma unroll
    for (int q = 0; q < 8; ++q) xe[q] = 0.f;
    for (int e = 0; e < 64; ++e) {
      float xv = s_xenc[u8*68 + e];
      float4 w0 = *(const float4*)&s_wx2[e*64 + grp*8];
      float4 w1 = *(const float4*)&s_wx2[e*64 + grp*8 + 4];
      xe[0]=fmaf(xv,w0.x,xe[0]); xe[1]=fmaf(xv,w0.y,xe[1]);
      xe[2]=fmaf(xv,w0.z,xe[2]); xe[3]=fmaf(xv,w0.w,xe[3]);
      xe[4]=fmaf(xv,w1.x,xe[4]); xe[5]=fmaf(xv,w1.y,xe[5]);
      xe[6]=fmaf(xv,w1.z,xe[6]); xe[7]=fmaf(xv,w1.w,xe[7]);
    }
#pragma unroll
    for (int q = 0; q < 8; ++q) pd_[q] = __expf(2.0f*xe[q]);
  }
  float dKr[64];
#pragma unroll
  for (int j = 0; j < 64; ++j) dKr[j] = dKg[j*256 + f];
  float wdd[8], wdc[8], advr[8];
  float vsum_d = 0.f;
#pragma unroll
  for (int jj = 0; jj < 8; ++jj) {
    wdd[jj]  = adW[(grp*8+jj)*64 + u8];
    wdc[jj]  = adW[(64+grp*8+jj)*64 + u8];
    advr[jj] = adv[grp*8+jj];
    vsum_d += advr[jj];
  }
  const float adb_u = adb[u8];
  __syncthreads();  // d2: Wd_x dead
  for (int i = tid; i < 4160; i += 512) s_wx2[i] = fcW[i];
  __syncthreads();  // d3

  // M1T[k=f][e] = sum_j fcW[e][j]*dK[j][k]
  for (int ee = 0; ee < 32; ++ee) {
    int e = half*32 + ee;
    float acc = 0.f;
#pragma unroll
    for (int j4 = 0; j4 < 16; ++j4) {
      float4 w = *(const float4*)&s_wx2[e*64 + j4*4];
      acc = fmaf(w.x, dKr[j4*4+0], acc);
      acc = fmaf(w.y, dKr[j4*4+1], acc);
      acc = fmaf(w.z, dKr[j4*4+2], acc);
      acc = fmaf(w.w, dKr[j4*4+3], acc);
    }
    s_buf[f*68 + e] = acc;
  }
  float m2k = 0.f, mbk = dbg[f];
#pragma unroll
  for (int j4 = 0; j4 < 16; ++j4) {
    float4 w  = *(const float4*)&s_wx2[4096 + j4*4];   // fcW row 64
    float4 fb = *(const float4*)&s_fcb[j4*4];
    m2k = fmaf(w.x,  dKr[j4*4+0], m2k); m2k = fmaf(w.y,  dKr[j4*4+1], m2k);
    m2k = fmaf(w.z,  dKr[j4*4+2], m2k); m2k = fmaf(w.w,  dKr[j4*4+3], m2k);
    mbk = fmaf(fb.x, dKr[j4*4+0], mbk); mbk = fmaf(fb.y, dKr[j4*4+1], mbk);
    mbk = fmaf(fb.z, dKr[j4*4+2], mbk); mbk = fmaf(fb.w, dKr[j4*4+3], mbk);
  }
  __syncthreads();  // d4: M1T visible; fcW reads done

  // XM_t[t][k=f] = sum_e xenc[t][e]*M1T[k][e]
  for (int tt = 0; tt < 32; ++tt) {
    int t = half*32 + tt;
    float acc = 0.f;
#pragma unroll
    for (int e4 = 0; e4 < 16; ++e4) {
      float4 xv = *(const float4*)&s_xenc[t*68 + e4*4];
      float4 mv = *(const float4*)&s_buf[f*68 + e4*4];
      acc = fmaf(xv.x, mv.x, acc); acc = fmaf(xv.y, mv.y, acc);
      acc = fmaf(xv.z, mv.z, acc); acc = fmaf(xv.w, mv.w, acc);
    }
    s_wx2[t*257 + f] = acc;
  }
  __syncthreads();  // d5: XM_t visible; M1T reads done

  // dR -> LDS [j][257] (first z read is after b1+b2 of step 0)
  for (int i = tid; i < 16384; i += 512)
    s_buf[(i >> 8)*257 + (i & 255)] = dRg[i];

  // ================= decoder loop (3 barriers/step) =================
  for (int t = 0; t < 64; ++t) {
    if (t > 0) {
      float gi = s_ag[lane], gf = s_ag[64+lane], gg = s_ag[128+lane], go = s_ag[192+lane];
      c_j = fmaf(gf, c_j, gi*gg);
      h_j = go * tanh_e(c_j);
      if (wv == 0) s_h[lane] = h_j;
    }
    // A: E_u
    float p = 0.f;
#pragma unroll
    for (int jj = 0; jj < 8; ++jj) {
      float hh = __shfl(h_j, grp*8 + jj);
      float cc = __shfl(c_j, grp*8 + jj);
      p = fmaf(hh, wdd[jj], p);
      p = fmaf(cc, wdc[jj], p);
    }
    p += __shfl_xor(p,1); p += __shfl_xor(p,2); p += __shfl_xor(p,4);
    float E = __expf(2.0f*(p + adb_u));
    if (grp == 0) s_hs[u8] = E;
    __syncthreads();  // b1

    // C: t'=u8, u-slice grp*8+[0,8)
    float4 E0 = *(const float4*)&s_hs[grp*8];
    float4 E1 = *(const float4*)&s_hs[grp*8+4];
    float sacc = 0.f;
    sacc = fmaf(advr[0], rcpf_(fmaf(E0.x, pd_[0], 1.f)), sacc);
    sacc = fmaf(advr[1], rcpf_(fmaf(E0.y, pd_[1], 1.f)), sacc);
    sacc = fmaf(advr[2], rcpf_(fmaf(E0.z, pd_[2], 1.f)), sacc);
    sacc = fmaf(advr[3], rcpf_(fmaf(E0.w, pd_[3], 1.f)), sacc);
    sacc = fmaf(advr[4], rcpf_(fmaf(E1.x, pd_[4], 1.f)), sacc);
    sacc = fmaf(advr[5], rcpf_(fmaf(E1.y, pd_[5], 1.f)), sacc);
    sacc = fmaf(advr[6], rcpf_(fmaf(E1.z, pd_[6], 1.f)), sacc);
    sacc = fmaf(advr[7], rcpf_(fmaf(E1.w, pd_[7], 1.f)), sacc);
    float sc = fmaf(-2.f, sacc, vsum_d);
    sc += __shfl_xor(sc,1); sc += __shfl_xor(sc,2); sc += __shfl_xor(sc,4);
    float pe = __expf(sc);
    if (grp == 0) s_pe[u8] = pe;
    float ws = pe;   // sum over the wave's 8 distinct t'
    ws += __shfl_xor(ws,8); ws += __shfl_xor(ws,16); ws += __shfl_xor(ws,32);
    if (lane == 0) s_redB[wv] = ws;
    __syncthreads();  // b2

    // z: invS*(pe.XM_t) + d.dR + y*m2 + mb
    float4 r0 = *(const float4*)&s_redB[0];
    float4 r1 = *(const float4*)&s_redB[4];
    float invS = rcpf_(((r0.x+r0.y)+(r0.z+r0.w)) + ((r1.x+r1.y)+(r1.z+r1.w)));
    float pa1 = 0.f;
#pragma unroll
    for (int tt = 0; tt < 32; ++tt)
      pa1 = fmaf(s_pe[half*32+tt], s_wx2[(half*32+tt)*257 + f], pa1);
    float pa2 = 0.f;
#pragma unroll
    for (int jj = 0; jj < 32; ++jj)
      pa2 = fmaf(s_h[half*32+jj], s_buf[(half*32+jj)*257 + f], pa2);
    float v = fmaf(pa1, invS, pa2);
    if (half == 0) v = fmaf(s_yprev[t], m2k, v + mbk);
    v += __shfl_xor(v, 1);
    float a = ((f >> 6) == 2) ? tanh_e(v) : sigm(v);
    if (half == 0) s_ag[f] = a;
    __syncthreads();  // b3
  }
  // final decoder update -> d_n
  {
    float gi = s_ag[lane], gf = s_ag[64+lane], gg = s_ag[128+lane], go = s_ag[192+lane];
    c_j = fmaf(gf, c_j, gi*gg);
    h_j = go * tanh_e(c_j);
    if (wv == 0) s_h[lane] = h_j;
  }
  // final context from last step's pe/S
  {
    float4 r0 = *(const float4*)&s_redB[0];
    float4 r1 = *(const float4*)&s_redB[4];
    float invS = rcpf_(((r0.x+r0.y)+(r0.z+r0.w)) + ((r1.x+r1.y)+(r1.z+r1.w)));
    float pc = 0.f;
#pragma unroll
    for (int q = 0; q < 8; ++q)
      pc = fmaf(s_pe[grp*8+q], s_xenc[(grp*8+q)*68 + u8], pc);
    pc += __shfl_xor(pc,1); pc += __shfl_xor(pc,2); pc += __shfl_xor(pc,4);
    if (grp == 0) s_ctx[u8] = pc * invS;
  }
  __syncthreads();  // d6

  // epilogue: out = [d_n, ctx] @ fcfW + fcfb
  {
    const float* fw  = fcfW + (size_t)(half*64)*256 + f;
    const float* src = half ? s_ctx : s_h;
    float pa = 0.f;
#pragma unroll
    for (int j = 0; j < 64; ++j)
      pa = fmaf(src[j], fw[(size_t)j*256], pa);
    pa += __shfl_xor(pa, 1);
    if (half == 0) out[b*256 + f] = pa + fcfb[f];
  }
}

extern "C" void kernel_launch(void* const* d_in, const int* in_sizes, int n_in,
                              void* d_out, int out_size, void* d_ws, size_t ws_size,
                              hipStream_t stream) {
  const float* gin  = (const float*)d_in[0];
  const float* eK   = (const float*)d_in[1];
  const float* eR   = (const float*)d_in[2];
  const float* eb   = (const float*)d_in[3];
  const float* dK   = (const float*)d_in[4];
  const float* dR   = (const float*)d_in[5];
  const float* db   = (const float*)d_in[6];
  const float* aeW  = (const float*)d_in[7];
  const float* aeb  = (const float*)d_in[8];
  const float* aev  = (const float*)d_in[9];
  // d_in[10] attn_e_vb, d_in[14] attn_d_vb: constant shifts, cancel in softmax
  const float* adW  = (const float*)d_in[11];
  const float* adb  = (const float*)d_in[12];
  const float* adv  = (const float*)d_in[13];
  const float* fcW  = (const float*)d_in[15];
  const float* fcb  = (const float*)d_in[16];
  const float* fcfW = (const float*)d_in[17];
  const float* fcfb = (const float*)d_in[18];
  float* out = (float*)d_out;

  const int B = in_sizes[0] / (64*256);
  hipLaunchKernelGGL(darnn_fused, dim3(B), dim3(512), 0, stream,
                     gin, eK, eR, eb, dK, dR, db, aeW, aeb, aev,
                     adW, adb, adv, fcW, fcb, fcfW, fcfb, out);
}